// Round 11
// baseline (113.877 us; speedup 1.0000x reference)
//
#include <hip/hip_runtime.h>

#define NBINS 256
#define NCOPY 32
#define GRID1 2048
#define TPB   256
// hist geometry: 512 thr x 1024 blocks = 4 blocks/CU (32 KiB LDS each),
// 32 waves/CU = HW occupancy cap, no residency tail.
#define HTPB  512
#define GRID2 1024

// Order-preserving float->uint encoding (monotone increasing).
__device__ __forceinline__ unsigned enc_f(float f) {
    unsigned u = __float_as_uint(f);
    return (u & 0x80000000u) ? ~u : (u | 0x80000000u);
}
__device__ __forceinline__ float dec_f(unsigned u) {
    unsigned v = (u & 0x80000000u) ? (u & 0x7FFFFFFFu) : ~u;
    return __uint_as_float(v);
}

// ws layout (uint32):
//   [0 .. GRID1)                 per-block min (enc), plain-stored every call
//   [GRID1 .. 2*GRID1)           per-block max (enc)
//   [2*GRID1 .. 2*GRID1+NBINS)   global hist bins (zeroed by pass1 block 0)
//   [2*GRID1+NBINS .. +2]        encoded global {min,max} (written by hrt_mid)

__device__ __forceinline__ void minmax16(const float4& a, const float4& b,
                                         const float4& c, const float4& d,
                                         float& lmin, float& lmax) {
    float mn = fminf(fminf(fminf(a.x, a.y), fminf(a.z, a.w)),
                     fminf(fminf(b.x, b.y), fminf(b.z, b.w)));
    mn = fminf(mn, fminf(fminf(fminf(c.x, c.y), fminf(c.z, c.w)),
                         fminf(fminf(d.x, d.y), fminf(d.z, d.w))));
    float mx = fmaxf(fmaxf(fmaxf(a.x, a.y), fmaxf(a.z, a.w)),
                     fmaxf(fmaxf(b.x, b.y), fmaxf(b.z, b.w)));
    mx = fmaxf(mx, fmaxf(fmaxf(fmaxf(c.x, c.y), fmaxf(c.z, c.w)),
                         fmaxf(fmaxf(d.x, d.y), fmaxf(d.z, d.w))));
    lmin = fminf(lmin, mn);
    lmax = fmaxf(lmax, mx);
}

__global__ __launch_bounds__(TPB) void hrt_pass1(
        const float4* __restrict__ in4, long n4,
        const float* __restrict__ in, long n,
        unsigned* __restrict__ pmin, unsigned* __restrict__ pmax,
        unsigned* __restrict__ hist) {
    const int tid = threadIdx.x;
    const int bid = blockIdx.x;

    // block 0 re-inits bins for this call (LLC-homed atomics; ordered vs
    // hist's atomicAdds by the kernel boundary)
    if (bid == 0) {
        for (int j = tid; j < NBINS; j += TPB) atomicExch(&hist[j], 0u);
    }

    float lmin = INFINITY, lmax = -INFINITY;
    const long stride = (long)GRID1 * TPB;
    long i = (long)bid * TPB + tid;
    for (; i + 3 * stride < n4; i += 4 * stride) {
        float4 a = in4[i];
        float4 b = in4[i + stride];
        float4 c = in4[i + 2 * stride];
        float4 d = in4[i + 3 * stride];
        minmax16(a, b, c, d, lmin, lmax);
    }
    for (; i < n4; i += stride) {
        float4 a = in4[i];
        lmin = fminf(lmin, fminf(fminf(a.x, a.y), fminf(a.z, a.w)));
        lmax = fmaxf(lmax, fmaxf(fmaxf(a.x, a.y), fmaxf(a.z, a.w)));
    }
    for (long j = n4 * 4 + (long)bid * TPB + tid; j < n; j += stride) {
        float v = in[j];
        lmin = fminf(lmin, v);
        lmax = fmaxf(lmax, v);
    }

    unsigned emin = enc_f(lmin), emax = enc_f(lmax);
    #pragma unroll
    for (int off = 32; off > 0; off >>= 1) {
        emin = min(emin, (unsigned)__shfl_down((int)emin, off));
        emax = max(emax, (unsigned)__shfl_down((int)emax, off));
    }
    __shared__ unsigned sred[8];
    const int wave = tid >> 6, lane = tid & 63;
    if (lane == 0) { sred[wave] = emin; sred[4 + wave] = emax; }
    __syncthreads();
    if (tid == 0) {
        unsigned m0 = min(min(sred[0], sred[1]), min(sred[2], sred[3]));
        unsigned m1 = max(max(sred[4], sred[5]), max(sred[6], sred[7]));
        pmin[bid] = m0;   // plain stores; kernel boundary publishes them
        pmax[bid] = m1;
    }
}

// Single block: reduce the 2*GRID1 partials once; publish enc'd tmin/tmax.
__global__ void hrt_mid(const unsigned* __restrict__ pmin,
                        const unsigned* __restrict__ pmax,
                        unsigned* __restrict__ mm) {
    __shared__ unsigned sred[16];
    const int tid = threadIdx.x;           // 512 threads
    const int wave = tid >> 6, lane = tid & 63;
    uint4 a = ((const uint4*)pmin)[tid];   // 512 x 4 = 2048 words
    uint4 b = ((const uint4*)pmax)[tid];
    unsigned gmin = min(min(a.x, a.y), min(a.z, a.w));
    unsigned gmax = max(max(b.x, b.y), max(b.z, b.w));
    #pragma unroll
    for (int off = 32; off > 0; off >>= 1) {
        gmin = min(gmin, (unsigned)__shfl_down((int)gmin, off));
        gmax = max(gmax, (unsigned)__shfl_down((int)gmax, off));
    }
    if (lane == 0) { sred[wave] = gmin; sred[8 + wave] = gmax; }
    __syncthreads();
    if (tid == 0) {
        unsigned m0 = sred[0], m1 = sred[8];
        #pragma unroll
        for (int w = 1; w < 8; ++w) {
            m0 = min(m0, sred[w]);
            m1 = max(m1, sred[8 + w]);
        }
        mm[0] = m0;   // plain stores; kernel boundary publishes them
        mm[1] = m1;
    }
}

// Histogram kernel: round-10 geometry, REVERSE traversal — pass1 streamed
// the tensor forward through the exactly-tensor-sized L3, so the tail is
// freshest; reading tail-first maximizes L3 hits.
__global__ __launch_bounds__(HTPB) void hrt_hist(
        const float4* __restrict__ in4, long n4,
        const float* __restrict__ in, long n,
        const unsigned* __restrict__ mm,
        unsigned* __restrict__ hist) {
    __shared__ unsigned lh[NBINS * NCOPY];
    for (int i = threadIdx.x; i < NBINS * NCOPY; i += HTPB) lh[i] = 0u;
    __syncthreads();
    const float tmin = dec_f(mm[0]);
    const float tmax = dec_f(mm[1]);
    const float scale = (float)NBINS / (tmax - tmin);
    const float bias = -tmin * scale;
    const int copy = threadIdx.x & (NCOPY - 1);
    const long tid = (long)blockIdx.x * HTPB + threadIdx.x;
    const long stride = (long)GRID2 * HTPB;

    #define HIST1(v)  do { \
        int ix = (int)fmaf((v), scale, bias); \
        ix = ix < 0 ? 0 : (ix > NBINS - 1 ? NBINS - 1 : ix); \
        atomicAdd(&lh[ix * NCOPY + copy], 1u); } while (0)
    #define HIST4(q)  do { HIST1((q).x); HIST1((q).y); HIST1((q).z); HIST1((q).w); } while (0)

    // scalar tail first (order irrelevant for correctness)
    for (long j = n4 * 4 + tid; j < n; j += stride)
        HIST1(in[j]);

    // reverse grid-stride walk: k = kmax .. 0
    long k = (tid < n4) ? ((n4 - 1 - tid) / stride) : -1;
    while (k >= 0 && (k & 3) != 3) {   // peel until remaining count % 4 == 0
        float4 a = in4[tid + k * stride];
        HIST4(a);
        --k;
    }
    for (; k >= 3; k -= 4) {           // descending 4-groups, freshest first
        long base = tid + (k - 3) * stride;
        float4 a = in4[base + 3 * stride];
        float4 b = in4[base + 2 * stride];
        float4 c = in4[base + stride];
        float4 d = in4[base];
        HIST4(a); HIST4(b); HIST4(c); HIST4(d);
    }

    #undef HIST1
    #undef HIST4
    __syncthreads();
    const int lane = threadIdx.x & 63;
    for (int b = threadIdx.x; b < NBINS; b += HTPB) {
        unsigned t = 0;
        #pragma unroll
        for (int c = 0; c < NCOPY; ++c) {
            int cc = (c + lane) & (NCOPY - 1);
            t += lh[b * NCOPY + cc];
        }
        if (t) atomicAdd(&hist[b], t);
    }
}

__global__ void hrt_fin(const unsigned* __restrict__ hist,
                        const unsigned* __restrict__ mm,
                        float* __restrict__ out) {
    if (threadIdx.x != 0 || blockIdx.x != 0) return;
    float tmin = dec_f(mm[0]);
    float tmax = dec_f(mm[1]);
    float total = 0.0f;
    for (int i = 0; i < NBINS; ++i) total += (float)hist[i];
    float tl = total * (1.0f - 0.99f) / 2.0f;
    float tu = total * (1.0f + 0.99f) / 2.0f;
    int lower = -1, upper = -1;
    float cum = 0.0f;
    for (int i = 0; i < NBINS; ++i) {
        cum += (float)hist[i];
        if (lower < 0 && cum > tl) lower = i;
        if (upper < 0 && cum > tu) upper = i;
    }
    if (lower < 0) lower = 0;
    if (upper < 0) upper = 0;
    float step = (tmax - tmin) / (float)NBINS;
    out[0] = tmin + step * (float)lower;
    out[1] = tmin + step * (float)upper;
}

extern "C" void kernel_launch(void* const* d_in, const int* in_sizes, int n_in,
                              void* d_out, int out_size, void* d_ws, size_t ws_size,
                              hipStream_t stream) {
    const float* in = (const float*)d_in[0];
    long n = (long)in_sizes[0];
    long n4 = n / 4;
    unsigned* ws = (unsigned*)d_ws;
    float* out = (float*)d_out;

    unsigned* pmin = ws;
    unsigned* pmax = ws + GRID1;
    unsigned* hist = ws + 2 * GRID1;
    unsigned* mm   = ws + 2 * GRID1 + NBINS;

    hrt_pass1<<<GRID1, TPB, 0, stream>>>((const float4*)in, n4, in, n,
                                         pmin, pmax, hist);
    hrt_mid<<<1, 512, 0, stream>>>(pmin, pmax, mm);
    hrt_hist<<<GRID2, HTPB, 0, stream>>>((const float4*)in, n4, in, n, mm, hist);
    hrt_fin<<<1, 1, 0, stream>>>(hist, mm, out);
}

// Round 12
// 86.692 us; speedup vs baseline: 1.3136x; 1.3136x over previous
//
#include <hip/hip_runtime.h>

#define NBINS 256
#define NCOPY 32        // fallback coarse-hist copies
#define FB    2048      // fine bins over [-8, 8], width 1/128
#define FSCALE 128.0f   // FB / 16
#define FBIAS  1024.0f  // +8 * FSCALE
#define P1G   1024
#define P1T   512
#define GRID2 1024
#define HTPB  512

// Order-preserving float->uint encoding (monotone increasing).
__device__ __forceinline__ unsigned enc_f(float f) {
    unsigned u = __float_as_uint(f);
    return (u & 0x80000000u) ? ~u : (u | 0x80000000u);
}
__device__ __forceinline__ float dec_f(unsigned u) {
    unsigned v = (u & 0x80000000u) ? (u & 0x7FFFFFFFu) : ~u;
    return __uint_as_float(v);
}

// ws layout (uint32):
//   [0 .. P1G)            per-block min (enc), plain-stored every call
//   [P1G .. 2*P1G)        per-block max (enc)
//   [2*P1G .. +NBINS)     coarse hist bins (fallback path; zeroed each call)
//   [2*P1G+NBINS .. +4)   mm: {enc min, enc max, flag_fine_valid, pad}
//   [2*P1G+NBINS+4 .. +FB) fine hist bins (zeroed each call)

__global__ void hrt_zero(unsigned* __restrict__ hist, unsigned* __restrict__ fine) {
    const int t = threadIdx.x;  // 1024
    if (t < NBINS) hist[t] = 0u;
    for (int j = t; j < FB; j += 1024) fine[j] = 0u;
}

// Single pass: exact min/max (registers) + fine histogram on fixed [-8,8].
__global__ __launch_bounds__(P1T) void hrt_pass1f(
        const float4* __restrict__ in4, long n4,
        const float* __restrict__ in, long n,
        unsigned* __restrict__ pmin, unsigned* __restrict__ pmax,
        unsigned* __restrict__ fine) {
    __shared__ unsigned fh[FB * 2];      // 16 KiB: 2 copies, copy = tid&1
    __shared__ unsigned sred[16];
    for (int j = threadIdx.x; j < FB * 2; j += P1T) fh[j] = 0u;
    __syncthreads();

    const int tid = threadIdx.x;
    const int bid = blockIdx.x;
    const int copy = tid & 1;
    float lmin = INFINITY, lmax = -INFINITY;
    const long stride = (long)P1G * P1T;

    #define PROC1(v) do { \
        float _x = (v); \
        lmin = fminf(lmin, _x); lmax = fmaxf(lmax, _x); \
        int ix = (int)fmaf(_x, FSCALE, FBIAS); \
        ix = ix < 0 ? 0 : (ix > FB - 1 ? FB - 1 : ix); \
        atomicAdd(&fh[ix * 2 + copy], 1u); } while (0)
    #define PROC4(q) do { PROC1((q).x); PROC1((q).y); PROC1((q).z); PROC1((q).w); } while (0)

    long i = (long)bid * P1T + tid;
    for (; i + 3 * stride < n4; i += 4 * stride) {
        float4 a = in4[i];
        float4 b = in4[i + stride];
        float4 c = in4[i + 2 * stride];
        float4 d = in4[i + 3 * stride];
        PROC4(a); PROC4(b); PROC4(c); PROC4(d);
    }
    for (; i < n4; i += stride) { float4 a = in4[i]; PROC4(a); }
    for (long j = n4 * 4 + (long)bid * P1T + tid; j < n; j += stride) PROC1(in[j]);
    #undef PROC1
    #undef PROC4

    unsigned emin = enc_f(lmin), emax = enc_f(lmax);
    #pragma unroll
    for (int off = 32; off > 0; off >>= 1) {
        emin = min(emin, (unsigned)__shfl_down((int)emin, off));
        emax = max(emax, (unsigned)__shfl_down((int)emax, off));
    }
    const int wave = tid >> 6, lane = tid & 63;
    if (lane == 0) { sred[wave] = emin; sred[8 + wave] = emax; }
    __syncthreads();   // also guarantees all fh atomics are complete
    if (tid == 0) {
        unsigned m0 = sred[0], m1 = sred[8];
        #pragma unroll
        for (int w = 1; w < P1T / 64; ++w) {
            m0 = min(m0, sred[w]);
            m1 = max(m1, sred[8 + w]);
        }
        pmin[bid] = m0;   // plain stores; kernel boundary publishes them
        pmax[bid] = m1;
    }
    // merge fine LDS hist -> global (one atomic per nonzero bin)
    for (int b = tid; b < FB; b += P1T) {
        unsigned t = fh[b * 2] + fh[b * 2 + 1];
        if (t) atomicAdd(&fine[b], t);
    }
}

// Reduce the P1G partials; publish enc min/max + fine-path validity flag.
__global__ void hrt_mid(const unsigned* __restrict__ pmin,
                        const unsigned* __restrict__ pmax,
                        unsigned* __restrict__ mm) {
    __shared__ unsigned sred[16];
    const int tid = threadIdx.x;           // 512 threads
    const int wave = tid >> 6, lane = tid & 63;
    uint2 a = ((const uint2*)pmin)[tid];   // 512 x 2 = 1024 words
    uint2 b = ((const uint2*)pmax)[tid];
    unsigned gmin = min(a.x, a.y);
    unsigned gmax = max(b.x, b.y);
    #pragma unroll
    for (int off = 32; off > 0; off >>= 1) {
        gmin = min(gmin, (unsigned)__shfl_down((int)gmin, off));
        gmax = max(gmax, (unsigned)__shfl_down((int)gmax, off));
    }
    if (lane == 0) { sred[wave] = gmin; sred[8 + wave] = gmax; }
    __syncthreads();
    if (tid == 0) {
        unsigned m0 = sred[0], m1 = sred[8];
        #pragma unroll
        for (int w = 1; w < 8; ++w) {
            m0 = min(m0, sred[w]);
            m1 = max(m1, sred[8 + w]);
        }
        mm[0] = m0;
        mm[1] = m1;
        float tmin = dec_f(m0), tmax = dec_f(m1);
        mm[2] = (tmin >= -8.0f && tmax <= 8.0f) ? 1u : 0u;
    }
}

// Fallback exact coarse histogram (round-10 proven). Early-exits when the
// fine histogram covers the data range.
__global__ __launch_bounds__(HTPB) void hrt_histfb(
        const float4* __restrict__ in4, long n4,
        const float* __restrict__ in, long n,
        const unsigned* __restrict__ mm,
        unsigned* __restrict__ hist) {
    if (mm[2] != 0u) return;   // fine path valid: nothing to do
    __shared__ unsigned lh[NBINS * NCOPY];
    for (int i = threadIdx.x; i < NBINS * NCOPY; i += HTPB) lh[i] = 0u;
    __syncthreads();
    const float tmin = dec_f(mm[0]);
    const float tmax = dec_f(mm[1]);
    const float scale = (float)NBINS / (tmax - tmin);
    const float bias = -tmin * scale;
    const int copy = threadIdx.x & (NCOPY - 1);
    const long tid = (long)blockIdx.x * HTPB + threadIdx.x;
    const long stride = (long)GRID2 * HTPB;

    #define HIST1(v)  do { \
        int ix = (int)fmaf((v), scale, bias); \
        ix = ix < 0 ? 0 : (ix > NBINS - 1 ? NBINS - 1 : ix); \
        atomicAdd(&lh[ix * NCOPY + copy], 1u); } while (0)
    #define HIST4(q)  do { HIST1((q).x); HIST1((q).y); HIST1((q).z); HIST1((q).w); } while (0)

    long i = tid;
    for (; i + 3 * stride < n4; i += 4 * stride) {
        float4 a = in4[i];
        float4 b = in4[i + stride];
        float4 c = in4[i + 2 * stride];
        float4 d = in4[i + 3 * stride];
        HIST4(a); HIST4(b); HIST4(c); HIST4(d);
    }
    for (; i < n4; i += stride) { float4 a = in4[i]; HIST4(a); }
    for (long j = n4 * 4 + tid; j < n; j += stride) HIST1(in[j]);
    #undef HIST1
    #undef HIST4
    __syncthreads();
    const int lane = threadIdx.x & 63;
    for (int b = threadIdx.x; b < NBINS; b += HTPB) {
        unsigned t = 0;
        #pragma unroll
        for (int c = 0; c < NCOPY; ++c) {
            int cc = (c + lane) & (NCOPY - 1);
            t += lh[b * NCOPY + cc];
        }
        if (t) atomicAdd(&hist[b], t);
    }
}

// Finalize: fine path maps the 2048-bin fixed-range histogram onto the 256
// reference bins via edge interpolation; fallback path uses coarse bins.
__global__ void hrt_fin(const unsigned* __restrict__ hist,
                        const unsigned* __restrict__ fine,
                        const unsigned* __restrict__ mm,
                        float* __restrict__ out) {
    __shared__ unsigned fu[FB];
    __shared__ double ssum[NBINS];
    __shared__ double sexc[NBINS];
    __shared__ double ccum[NBINS];
    __shared__ double sdtot;
    const int tid = threadIdx.x;   // 256
    const float tmin = dec_f(mm[0]);
    const float tmax = dec_f(mm[1]);

    if (mm[2] != 0u) {
        // ---- fine path ----
        double s = 0.0;
        #pragma unroll
        for (int k = 0; k < 8; ++k) {
            unsigned v = fine[tid * 8 + k];
            fu[tid * 8 + k] = v;
            s += (double)v;
        }
        ssum[tid] = s;
        __syncthreads();
        if (tid == 0) {
            double run = 0.0;
            for (int g = 0; g < NBINS; ++g) { sexc[g] = run; run += ssum[g]; }
            sdtot = run;
        }
        __syncthreads();
        const double total = sdtot;
        const double stepd = ((double)tmax - (double)tmin) / 256.0;
        // thread b: ccum[b] = count(x in coarse bins 0..b) ~= F(e_{b+1})
        {
            double F;
            if (tid == 255) {
                F = total;
            } else {
                double e = (double)tmin + stepd * (double)(tid + 1);
                double p = (e + 8.0) * 128.0;     // position in fine-bin space
                if (p < 0.0) p = 0.0;
                if (p > (double)FB) p = (double)FB;
                int ii = (int)p;
                double frac = p - (double)ii;
                if (ii >= FB) { ii = FB - 1; frac = 1.0; }
                double cumi = sexc[ii >> 3];
                for (int k = (ii & ~7); k < ii; ++k) cumi += (double)fu[k];
                F = cumi + frac * (double)fu[ii];
            }
            ccum[tid] = F;
        }
        __syncthreads();
        if (tid == 0) {
            double tl = total * 0.005;
            double tu = total * 0.995;
            int lower = -1, upper = -1;
            for (int b = 0; b < NBINS; ++b) {
                if (lower < 0 && ccum[b] > tl) lower = b;
                if (upper < 0 && ccum[b] > tu) upper = b;
            }
            if (lower < 0) lower = 0;
            if (upper < 0) upper = 0;
            out[0] = (float)((double)tmin + stepd * (double)lower);
            out[1] = (float)((double)tmin + stepd * (double)upper);
        }
    } else {
        // ---- fallback coarse path (round-10 fin) ----
        if (tid == 0) {
            float total = 0.0f;
            for (int i = 0; i < NBINS; ++i) total += (float)hist[i];
            float tl = total * (1.0f - 0.99f) / 2.0f;
            float tu = total * (1.0f + 0.99f) / 2.0f;
            int lower = -1, upper = -1;
            float cum = 0.0f;
            for (int i = 0; i < NBINS; ++i) {
                cum += (float)hist[i];
                if (lower < 0 && cum > tl) lower = i;
                if (upper < 0 && cum > tu) upper = i;
            }
            if (lower < 0) lower = 0;
            if (upper < 0) upper = 0;
            float step = (tmax - tmin) / (float)NBINS;
            out[0] = tmin + step * (float)lower;
            out[1] = tmin + step * (float)upper;
        }
    }
}

extern "C" void kernel_launch(void* const* d_in, const int* in_sizes, int n_in,
                              void* d_out, int out_size, void* d_ws, size_t ws_size,
                              hipStream_t stream) {
    const float* in = (const float*)d_in[0];
    long n = (long)in_sizes[0];
    long n4 = n / 4;
    unsigned* ws = (unsigned*)d_ws;
    float* out = (float*)d_out;

    unsigned* pmin = ws;
    unsigned* pmax = ws + P1G;
    unsigned* hist = ws + 2 * P1G;
    unsigned* mm   = ws + 2 * P1G + NBINS;
    unsigned* fine = ws + 2 * P1G + NBINS + 4;

    hrt_zero<<<1, 1024, 0, stream>>>(hist, fine);
    hrt_pass1f<<<P1G, P1T, 0, stream>>>((const float4*)in, n4, in, n,
                                        pmin, pmax, fine);
    hrt_mid<<<1, 512, 0, stream>>>(pmin, pmax, mm);
    hrt_histfb<<<GRID2, HTPB, 0, stream>>>((const float4*)in, n4, in, n, mm, hist);
    hrt_fin<<<1, 256, 0, stream>>>(hist, fine, mm, out);
}